// Round 1
// baseline (13887.975 us; speedup 1.0000x reference)
//
#include <hip/hip_runtime.h>
#include <hip/hip_bf16.h>
#include <math.h>

#define BATCH   2
#define SEQ     2048
#define DM      2048
#define NH      16
#define QKR     64
#define QKN     128
#define KVL     512
#define VD      128
#define QKD     192     // QKN + QKR
#define RMS_EPS 1.1920928955078125e-07f

// ---------------- generic tiled fp32 GEMM: C[M,N] = A[M,K] @ B[K,N] ----------------
// grid = (N/64, M/64), block = 256. All dims assumed multiples of tile sizes.
__global__ __launch_bounds__(256) void gemm_f32(const float* __restrict__ A,
                                                const float* __restrict__ B,
                                                float* __restrict__ C,
                                                int K, int lda, int ldb, int ldc)
{
    __shared__ float As[16][64];
    __shared__ float Bs[16][64];
    const int tid = threadIdx.x;
    const int tx = tid & 15, ty = tid >> 4;
    const int row0 = blockIdx.y * 64, col0 = blockIdx.x * 64;
    const int am = tid >> 2, ak = (tid & 3) * 4;   // A-tile load coords (64 x 16)
    const int bk = tid >> 4, bn = (tid & 15) * 4;  // B-tile load coords (16 x 64)
    float acc[4][4] = {};

    for (int k0 = 0; k0 < K; k0 += 16) {
        float4 a4 = *reinterpret_cast<const float4*>(&A[(size_t)(row0 + am) * lda + k0 + ak]);
        float4 b4 = *reinterpret_cast<const float4*>(&B[(size_t)(k0 + bk) * ldb + col0 + bn]);
        As[ak + 0][am] = a4.x;
        As[ak + 1][am] = a4.y;
        As[ak + 2][am] = a4.z;
        As[ak + 3][am] = a4.w;
        *reinterpret_cast<float4*>(&Bs[bk][bn]) = b4;
        __syncthreads();
        #pragma unroll
        for (int kk = 0; kk < 16; ++kk) {
            float4 a = *reinterpret_cast<const float4*>(&As[kk][ty * 4]);
            float4 b = *reinterpret_cast<const float4*>(&Bs[kk][tx * 4]);
            acc[0][0] += a.x * b.x; acc[0][1] += a.x * b.y; acc[0][2] += a.x * b.z; acc[0][3] += a.x * b.w;
            acc[1][0] += a.y * b.x; acc[1][1] += a.y * b.y; acc[1][2] += a.y * b.z; acc[1][3] += a.y * b.w;
            acc[2][0] += a.z * b.x; acc[2][1] += a.z * b.y; acc[2][2] += a.z * b.z; acc[2][3] += a.z * b.w;
            acc[3][0] += a.w * b.x; acc[3][1] += a.w * b.y; acc[3][2] += a.w * b.z; acc[3][3] += a.w * b.w;
        }
        __syncthreads();
    }
    #pragma unroll
    for (int i = 0; i < 4; ++i) {
        float4 o = make_float4(acc[i][0], acc[i][1], acc[i][2], acc[i][3]);
        *reinterpret_cast<float4*>(&C[(size_t)(row0 + ty * 4 + i) * ldc + col0 + tx * 4]) = o;
    }
}

// ---------------- RoPE on q (in-place on columns [h*192+128, h*192+192)) ----------------
__global__ void rope_q_kernel(float* __restrict__ q)
{
    int idx = blockIdx.x * blockDim.x + threadIdx.x;   // BATCH*SEQ*NH*32 threads
    int i = idx & 31;
    int h = (idx >> 5) & 15;
    int s = (idx >> 9) & 2047;
    int b = idx >> 20;
    double freq = pow(10000.0, -(double)(2 * i) / 64.0);
    double t = (double)s * freq;
    float c = (float)cos(t), sn = (float)sin(t);
    float* p = q + ((size_t)(b * SEQ + s)) * (NH * QKD) + h * QKD + QKN + 2 * i;
    float x1 = p[0], x2 = p[1];
    p[0] = x1 * c - x2 * sn;
    p[1] = x2 * c + x1 * sn;
}

// ---------------- RoPE on k_rope (in-place on kv_a columns [512,576)) ----------------
__global__ void rope_k_kernel(float* __restrict__ kva)
{
    int idx = blockIdx.x * blockDim.x + threadIdx.x;   // BATCH*SEQ*32 threads
    int i = idx & 31;
    int s = (idx >> 5) & 2047;
    int b = idx >> 16;
    double freq = pow(10000.0, -(double)(2 * i) / 64.0);
    double t = (double)s * freq;
    float c = (float)cos(t), sn = (float)sin(t);
    float* p = kva + ((size_t)(b * SEQ + s)) * (KVL + QKR) + KVL + 2 * i;
    float x1 = p[0], x2 = p[1];
    p[0] = x1 * c - x2 * sn;
    p[1] = x2 * c + x1 * sn;
}

// ---------------- RMSNorm on c_kv (first 512 cols of kv_a), in place ----------------
__global__ __launch_bounds__(256) void rmsnorm_kernel(float* __restrict__ kva,
                                                      const float* __restrict__ w)
{
    const int rid = blockIdx.x;                // B*S rows
    float* row = kva + (size_t)rid * (KVL + QKR);
    const int tid = threadIdx.x;
    float v[2];
    float ss = 0.f;
    #pragma unroll
    for (int j = 0; j < 2; ++j) {
        int d = tid + j * 256;
        v[j] = row[d];
        ss += v[j] * v[j];
    }
    #pragma unroll
    for (int off = 32; off > 0; off >>= 1) ss += __shfl_down(ss, off, 64);
    __shared__ float red[4];
    if ((tid & 63) == 0) red[tid >> 6] = ss;
    __syncthreads();
    float total = red[0] + red[1] + red[2] + red[3];
    float scale = 1.0f / sqrtf(total * (1.0f / KVL) + RMS_EPS);
    #pragma unroll
    for (int j = 0; j < 2; ++j) {
        int d = tid + j * 256;
        row[d] = v[j] * scale * w[d];
    }
}

// ---------------- causal attention, one block per (q-row, head, batch) ----------------
// q: [B,S,NH*192]  kvb: [B,S,NH*256] (nope|v)  kva: [B,S,576] (rope at col 512)
// obuf: [B,S,NH*128]
__global__ __launch_bounds__(256) void attn_kernel(const float* __restrict__ qbuf,
                                                   const float* __restrict__ kvb,
                                                   const float* __restrict__ kva,
                                                   float* __restrict__ obuf)
{
    const int qi = blockIdx.x, h = blockIdx.y, b = blockIdx.z;
    __shared__ __align__(16) float q_s[QKD];
    __shared__ float sc[SEQ];
    __shared__ float red[4];
    __shared__ float red2[256];
    const int tid = threadIdx.x;
    const float scale = 0.07216878364870323f;  // 1/sqrt(192)

    const float* qp = qbuf + ((size_t)(b * SEQ + qi)) * (NH * QKD) + h * QKD;
    for (int i = tid; i < QKD; i += 256) q_s[i] = qp[i];
    __syncthreads();

    const int nk = qi + 1;
    const float4* q4 = reinterpret_cast<const float4*>(q_s);
    for (int k = tid; k < nk; k += 256) {
        const float4* kn = reinterpret_cast<const float4*>(kvb + ((size_t)(b * SEQ + k)) * (NH * 256) + h * 256);
        const float4* kr = reinterpret_cast<const float4*>(kva + ((size_t)(b * SEQ + k)) * (KVL + QKR) + KVL);
        float acc = 0.f;
        #pragma unroll
        for (int d = 0; d < 32; ++d) {
            float4 kv = kn[d]; float4 qq = q4[d];
            acc += qq.x * kv.x + qq.y * kv.y + qq.z * kv.z + qq.w * kv.w;
        }
        #pragma unroll
        for (int d = 0; d < 16; ++d) {
            float4 kv = kr[d]; float4 qq = q4[32 + d];
            acc += qq.x * kv.x + qq.y * kv.y + qq.z * kv.z + qq.w * kv.w;
        }
        sc[k] = acc * scale;
    }
    __syncthreads();

    // block max
    float m = -INFINITY;
    for (int k = tid; k < nk; k += 256) m = fmaxf(m, sc[k]);
    #pragma unroll
    for (int off = 32; off > 0; off >>= 1) m = fmaxf(m, __shfl_down(m, off, 64));
    if ((tid & 63) == 0) red[tid >> 6] = m;
    __syncthreads();
    m = fmaxf(fmaxf(red[0], red[1]), fmaxf(red[2], red[3]));

    // exp + block sum
    float s = 0.f;
    for (int k = tid; k < nk; k += 256) {
        float p = expf(sc[k] - m);
        sc[k] = p;
        s += p;
    }
    #pragma unroll
    for (int off = 32; off > 0; off >>= 1) s += __shfl_down(s, off, 64);
    __syncthreads();                       // sc writes + red reuse barrier
    if ((tid & 63) == 0) red[tid >> 6] = s;
    __syncthreads();
    const float inv_sum = 1.0f / (red[0] + red[1] + red[2] + red[3]);

    // out = sum_k p[k] * v[k][:]   (128 dims, 2 key-halves per dim)
    const int d = tid & 127, half = tid >> 7;
    float acc = 0.f;
    for (int k = half; k < nk; k += 2)
        acc += sc[k] * kvb[((size_t)(b * SEQ + k)) * (NH * 256) + h * 256 + 128 + d];
    red2[tid] = acc;
    __syncthreads();
    if (tid < 128)
        obuf[((size_t)(b * SEQ + qi)) * (NH * VD) + h * VD + tid] =
            (red2[tid] + red2[tid + 128]) * inv_sum;
}

extern "C" void kernel_launch(void* const* d_in, const int* in_sizes, int n_in,
                              void* d_out, int out_size, void* d_ws, size_t ws_size,
                              hipStream_t stream)
{
    const float* x         = (const float*)d_in[0];
    const float* Wq        = (const float*)d_in[1];
    const float* Wkv_a     = (const float*)d_in[2];
    const float* kv_norm_w = (const float*)d_in[3];
    const float* Wkv_b     = (const float*)d_in[4];
    const float* Wo        = (const float*)d_in[5];
    float* out = (float*)d_out;

    float* ws = (float*)d_ws;
    float* q_raw  = ws;                                           // B*S*NH*192 = 12,582,912
    float* kv_a   = q_raw + (size_t)BATCH * SEQ * NH * QKD;       // B*S*576    =  2,359,296
    float* kv_b   = kv_a  + (size_t)BATCH * SEQ * (KVL + QKR);    // B*S*NH*256 = 16,777,216
    float* attn_o = kv_b  + (size_t)BATCH * SEQ * NH * 256;       // B*S*NH*128 =  8,388,608

    const int M = BATCH * SEQ;   // 4096
    dim3 blk(256);

    // q = x @ Wq            (4096 x 3072, K=2048)
    gemm_f32<<<dim3(3072 / 64, M / 64), blk, 0, stream>>>(x, Wq, q_raw, DM, DM, NH * QKD, NH * QKD);
    // kv_a = x @ Wkv_a      (4096 x 576, K=2048)
    gemm_f32<<<dim3(576 / 64, M / 64), blk, 0, stream>>>(x, Wkv_a, kv_a, DM, DM, KVL + QKR, KVL + QKR);
    // rope
    rope_q_kernel<<<(BATCH * SEQ * NH * 32) / 256, blk, 0, stream>>>(q_raw);
    rope_k_kernel<<<(BATCH * SEQ * 32) / 256, blk, 0, stream>>>(kv_a);
    // rmsnorm c_kv in place
    rmsnorm_kernel<<<M, blk, 0, stream>>>(kv_a, kv_norm_w);
    // kv_b = c_kv_norm @ Wkv_b   (4096 x 4096, K=512, A has row stride 576)
    gemm_f32<<<dim3(4096 / 64, M / 64), blk, 0, stream>>>(kv_a, Wkv_b, kv_b, KVL, KVL + QKR, NH * 256, NH * 256);
    // attention
    attn_kernel<<<dim3(SEQ, NH, BATCH), blk, 0, stream>>>(q_raw, kv_b, kv_a, attn_o);
    // out = attn_o @ Wo     (4096 x 2048, K=2048)
    gemm_f32<<<dim3(2048 / 64, M / 64), blk, 0, stream>>>(attn_o, Wo, out, NH * VD, NH * VD, DM, DM);
}

// Round 2
// 2103.073 us; speedup vs baseline: 6.6037x; 6.6037x over previous
//
#include <hip/hip_runtime.h>
#include <hip/hip_bf16.h>
#include <math.h>

#define BATCH   2
#define SEQ     2048
#define DM      2048
#define NH      16
#define QKR     64
#define QKN     128
#define KVL     512
#define VD      128
#define QKD     192     // QKN + QKR
#define RMS_EPS 1.1920928955078125e-07f

typedef __bf16 bf16x8 __attribute__((ext_vector_type(8)));
typedef float  f32x4  __attribute__((ext_vector_type(4)));

// ---------------- generic tiled fp32 GEMM: C[M,N] = A[M,K] @ B[K,N] ----------------
__global__ __launch_bounds__(256) void gemm_f32(const float* __restrict__ A,
                                                const float* __restrict__ B,
                                                float* __restrict__ C,
                                                int K, int lda, int ldb, int ldc)
{
    __shared__ float As[16][64];
    __shared__ float Bs[16][64];
    const int tid = threadIdx.x;
    const int tx = tid & 15, ty = tid >> 4;
    const int row0 = blockIdx.y * 64, col0 = blockIdx.x * 64;
    const int am = tid >> 2, ak = (tid & 3) * 4;
    const int bk = tid >> 4, bn = (tid & 15) * 4;
    float acc[4][4] = {};

    for (int k0 = 0; k0 < K; k0 += 16) {
        float4 a4 = *reinterpret_cast<const float4*>(&A[(size_t)(row0 + am) * lda + k0 + ak]);
        float4 b4 = *reinterpret_cast<const float4*>(&B[(size_t)(k0 + bk) * ldb + col0 + bn]);
        As[ak + 0][am] = a4.x;
        As[ak + 1][am] = a4.y;
        As[ak + 2][am] = a4.z;
        As[ak + 3][am] = a4.w;
        *reinterpret_cast<float4*>(&Bs[bk][bn]) = b4;
        __syncthreads();
        #pragma unroll
        for (int kk = 0; kk < 16; ++kk) {
            float4 a = *reinterpret_cast<const float4*>(&As[kk][ty * 4]);
            float4 b = *reinterpret_cast<const float4*>(&Bs[kk][tx * 4]);
            acc[0][0] += a.x * b.x; acc[0][1] += a.x * b.y; acc[0][2] += a.x * b.z; acc[0][3] += a.x * b.w;
            acc[1][0] += a.y * b.x; acc[1][1] += a.y * b.y; acc[1][2] += a.y * b.z; acc[1][3] += a.y * b.w;
            acc[2][0] += a.z * b.x; acc[2][1] += a.z * b.y; acc[2][2] += a.z * b.z; acc[2][3] += a.z * b.w;
            acc[3][0] += a.w * b.x; acc[3][1] += a.w * b.y; acc[3][2] += a.w * b.z; acc[3][3] += a.w * b.w;
        }
        __syncthreads();
    }
    #pragma unroll
    for (int i = 0; i < 4; ++i) {
        float4 o = make_float4(acc[i][0], acc[i][1], acc[i][2], acc[i][3]);
        *reinterpret_cast<float4*>(&C[(size_t)(row0 + ty * 4 + i) * ldc + col0 + tx * 4]) = o;
    }
}

// ---------------- RoPE on q ----------------
__global__ void rope_q_kernel(float* __restrict__ q)
{
    int idx = blockIdx.x * blockDim.x + threadIdx.x;
    int i = idx & 31;
    int h = (idx >> 5) & 15;
    int s = (idx >> 9) & 2047;
    int b = idx >> 20;
    double freq = pow(10000.0, -(double)(2 * i) / 64.0);
    double t = (double)s * freq;
    float c = (float)cos(t), sn = (float)sin(t);
    float* p = q + ((size_t)(b * SEQ + s)) * (NH * QKD) + h * QKD + QKN + 2 * i;
    float x1 = p[0], x2 = p[1];
    p[0] = x1 * c - x2 * sn;
    p[1] = x2 * c + x1 * sn;
}

// ---------------- RoPE on k_rope ----------------
__global__ void rope_k_kernel(float* __restrict__ kva)
{
    int idx = blockIdx.x * blockDim.x + threadIdx.x;
    int i = idx & 31;
    int s = (idx >> 5) & 2047;
    int b = idx >> 16;
    double freq = pow(10000.0, -(double)(2 * i) / 64.0);
    double t = (double)s * freq;
    float c = (float)cos(t), sn = (float)sin(t);
    float* p = kva + ((size_t)(b * SEQ + s)) * (KVL + QKR) + KVL + 2 * i;
    float x1 = p[0], x2 = p[1];
    p[0] = x1 * c - x2 * sn;
    p[1] = x2 * c + x1 * sn;
}

// ---------------- RMSNorm on c_kv ----------------
__global__ __launch_bounds__(256) void rmsnorm_kernel(float* __restrict__ kva,
                                                      const float* __restrict__ w)
{
    const int rid = blockIdx.x;
    float* row = kva + (size_t)rid * (KVL + QKR);
    const int tid = threadIdx.x;
    float v[2];
    float ss = 0.f;
    #pragma unroll
    for (int j = 0; j < 2; ++j) {
        int d = tid + j * 256;
        v[j] = row[d];
        ss += v[j] * v[j];
    }
    #pragma unroll
    for (int off = 32; off > 0; off >>= 1) ss += __shfl_down(ss, off, 64);
    __shared__ float red[4];
    if ((tid & 63) == 0) red[tid >> 6] = ss;
    __syncthreads();
    float total = red[0] + red[1] + red[2] + red[3];
    float scale = 1.0f / sqrtf(total * (1.0f / KVL) + RMS_EPS);
    #pragma unroll
    for (int j = 0; j < 2; ++j) {
        int d = tid + j * 256;
        row[d] = v[j] * scale * w[d];
    }
}

// ---------------- build bf16 K = [nope | rope] : [B,H,S,192] ----------------
__global__ __launch_bounds__(256) void build_k(const float* __restrict__ kvb,
                                               const float* __restrict__ kva,
                                               __bf16* __restrict__ Kb)
{
    int idx = blockIdx.x * 256 + threadIdx.x;       // B*H*S*192 threads
    int d = idx % 192;
    int s = (idx / 192) & 2047;
    int hb = idx / (192 * 2048);
    int h = hb & 15, b = hb >> 4;
    float v;
    if (d < 128) v = kvb[((size_t)(b * SEQ + s)) * (NH * 256) + h * 256 + d];
    else         v = kva[((size_t)(b * SEQ + s)) * (KVL + QKR) + KVL + (d - 128)];
    Kb[idx] = (__bf16)v;
}

// ---------------- build bf16 V^T : [B,H,128,S] ----------------
__global__ __launch_bounds__(256) void build_vt(const float* __restrict__ kvb,
                                                __bf16* __restrict__ Vt)
{
    __shared__ float tile[64][129];
    const int s0 = blockIdx.x * 64, h = blockIdx.y, b = blockIdx.z;
    const int t = threadIdx.x;
    #pragma unroll
    for (int i = 0; i < 8; ++i) {
        int flat = i * 256 + t;                     // 0..2047 : 64 rows x 32 float4
        int sl = flat >> 5, f4 = flat & 31;
        float4 v = *reinterpret_cast<const float4*>(
            &kvb[((size_t)(b * SEQ + s0 + sl)) * (NH * 256) + h * 256 + 128 + f4 * 4]);
        tile[sl][f4 * 4 + 0] = v.x; tile[sl][f4 * 4 + 1] = v.y;
        tile[sl][f4 * 4 + 2] = v.z; tile[sl][f4 * 4 + 3] = v.w;
    }
    __syncthreads();
    #pragma unroll
    for (int j = 0; j < 32; ++j) {
        int flat = j * 256 + t;                     // 0..8191 : 128 d x 64 s
        int d = flat >> 6, sl = flat & 63;
        Vt[((size_t)((b * NH + h) * VD + d)) * SEQ + s0 + sl] = (__bf16)tile[sl][d];
    }
}

// ---------------- MFMA flash attention ----------------
// qb: [B,S,NH*192] fp32 (rope applied); Kb: [B,H,S,192] bf16; Vt: [B,H,128,S] bf16
// ob: [B,S,NH*128] fp32
#define LKS 200   // 192 + 8 pad (bf16)
#define LVS 72    // 64 + 8
#define LPS 72
__global__ __launch_bounds__(256) void attn_mfma(const float* __restrict__ qb,
                                                 const __bf16* __restrict__ Kb,
                                                 const __bf16* __restrict__ Vt,
                                                 float* __restrict__ ob)
{
    __shared__ __bf16 Ks[64 * LKS];        // 25600 B
    __shared__ __bf16 Vs[128 * LVS];       // 18432 B
    __shared__ __bf16 Ps[4 * 16 * LPS];    //  9216 B
    const int tid = threadIdx.x;
    const int wave = tid >> 6, lane = tid & 63;
    const int n = lane & 15, quad = lane >> 4;
    const int qt = blockIdx.x, h = blockIdx.y, b = blockIdx.z;
    const int q0 = qt * 64;
    const int bh = b * NH + h;
    const float scale = 0.07216878364870323f;   // 1/sqrt(192)

    // Q fragments: wave handles q-rows q0+wave*16 .. +15; A-layout [m=n][k=quad*8+j]
    bf16x8 qfrag[6];
    const int qrow = q0 + wave * 16 + n;
    const float* qp = qb + ((size_t)(b * SEQ + qrow)) * (NH * QKD) + h * QKD + quad * 8;
    #pragma unroll
    for (int c = 0; c < 6; ++c) {
        float4 u0 = *reinterpret_cast<const float4*>(qp + c * 32);
        float4 u1 = *reinterpret_cast<const float4*>(qp + c * 32 + 4);
        bf16x8 f;
        f[0] = (__bf16)u0.x; f[1] = (__bf16)u0.y; f[2] = (__bf16)u0.z; f[3] = (__bf16)u0.w;
        f[4] = (__bf16)u1.x; f[5] = (__bf16)u1.y; f[6] = (__bf16)u1.z; f[7] = (__bf16)u1.w;
        qfrag[c] = f;
    }

    f32x4 Oa[8];
    #pragma unroll
    for (int i = 0; i < 8; ++i)
        #pragma unroll
        for (int r = 0; r < 4; ++r) Oa[i][r] = 0.f;
    float m_i[4], l_i[4];
    #pragma unroll
    for (int r = 0; r < 4; ++r) { m_i[r] = -1e30f; l_i[r] = 0.f; }

    const __bf16* Kg = Kb + (size_t)bh * SEQ * QKD;
    const __bf16* Vg = Vt + (size_t)bh * VD * SEQ;
    const int ntiles = qt + 1;

    for (int kt = 0; kt < ntiles; ++kt) {
        const int k0 = kt * 64;
        __syncthreads();
        // stage K tile: 64 keys x 192 bf16 (1536 16B chunks)
        #pragma unroll
        for (int i = 0; i < 6; ++i) {
            int flat = i * 256 + tid;
            int key = flat / 24, c8 = flat % 24;
            bf16x8 v = *reinterpret_cast<const bf16x8*>(Kg + (size_t)(k0 + key) * QKD + c8 * 8);
            *reinterpret_cast<bf16x8*>(&Ks[key * LKS + c8 * 8]) = v;
        }
        // stage V^T tile: 128 d x 64 keys (1024 16B chunks)
        #pragma unroll
        for (int i = 0; i < 4; ++i) {
            int flat = i * 256 + tid;
            int d = flat >> 3, c8 = flat & 7;
            bf16x8 v = *reinterpret_cast<const bf16x8*>(Vg + (size_t)d * SEQ + k0 + c8 * 8);
            *reinterpret_cast<bf16x8*>(&Vs[d * LVS + c8 * 8]) = v;
        }
        __syncthreads();

        // scores: S[16q x 64k] per wave, 4 key-subtiles x 6 d-chunks
        f32x4 sacc[4];
        #pragma unroll
        for (int t = 0; t < 4; ++t) {
            f32x4 a;
            #pragma unroll
            for (int r = 0; r < 4; ++r) a[r] = 0.f;
            #pragma unroll
            for (int c = 0; c < 6; ++c) {
                bf16x8 kf = *reinterpret_cast<const bf16x8*>(&Ks[(t * 16 + n) * LKS + c * 32 + quad * 8]);
                a = __builtin_amdgcn_mfma_f32_16x16x32_bf16(qfrag[c], kf, a, 0, 0, 0);
            }
            sacc[t] = a;
        }

        // mask + online softmax (C-layout: row q = quad*4+r, col key = 16t+n)
        const int qg = q0 + wave * 16 + quad * 4;
        float mloc[4];
        #pragma unroll
        for (int r = 0; r < 4; ++r) mloc[r] = -1e30f;
        #pragma unroll
        for (int t = 0; t < 4; ++t) {
            int key = k0 + t * 16 + n;
            #pragma unroll
            for (int r = 0; r < 4; ++r) {
                float s = sacc[t][r] * scale;
                s = (key <= qg + r) ? s : -1e30f;
                sacc[t][r] = s;
                mloc[r] = fmaxf(mloc[r], s);
            }
        }
        #pragma unroll
        for (int off = 1; off < 16; off <<= 1)
            #pragma unroll
            for (int r = 0; r < 4; ++r)
                mloc[r] = fmaxf(mloc[r], __shfl_xor(mloc[r], off, 64));
        float alpha[4], sum[4];
        #pragma unroll
        for (int r = 0; r < 4; ++r) {
            float mn = fmaxf(m_i[r], mloc[r]);
            alpha[r] = __expf(m_i[r] - mn);
            m_i[r] = mn;
            sum[r] = 0.f;
        }
        #pragma unroll
        for (int t = 0; t < 4; ++t)
            #pragma unroll
            for (int r = 0; r < 4; ++r) {
                float p = __expf(sacc[t][r] - m_i[r]);
                sum[r] += p;
                Ps[wave * 16 * LPS + (quad * 4 + r) * LPS + t * 16 + n] = (__bf16)p;
            }
        #pragma unroll
        for (int off = 1; off < 16; off <<= 1)
            #pragma unroll
            for (int r = 0; r < 4; ++r)
                sum[r] += __shfl_xor(sum[r], off, 64);
        #pragma unroll
        for (int r = 0; r < 4; ++r) l_i[r] = l_i[r] * alpha[r] + sum[r];
        #pragma unroll
        for (int i = 0; i < 8; ++i)
            #pragma unroll
            for (int r = 0; r < 4; ++r) Oa[i][r] *= alpha[r];

        // drain P writes (per-wave region; in-wave ordering only)
        __asm__ volatile("s_waitcnt lgkmcnt(0)" ::: "memory");

        // PV: O[16q x 128vd] += P[16x64] * V[64x128]
        #pragma unroll
        for (int kc = 0; kc < 2; ++kc) {
            bf16x8 pf = *reinterpret_cast<const bf16x8*>(&Ps[wave * 16 * LPS + n * LPS + kc * 32 + quad * 8]);
            #pragma unroll
            for (int vt = 0; vt < 8; ++vt) {
                bf16x8 vf = *reinterpret_cast<const bf16x8*>(&Vs[(vt * 16 + n) * LVS + kc * 32 + quad * 8]);
                Oa[vt] = __builtin_amdgcn_mfma_f32_16x16x32_bf16(pf, vf, Oa[vt], 0, 0, 0);
            }
        }
    }

    // epilogue
    #pragma unroll
    for (int r = 0; r < 4; ++r) {
        float inv = 1.0f / l_i[r];
        int row = q0 + wave * 16 + quad * 4 + r;
        float* op = ob + ((size_t)(b * SEQ + row)) * (NH * VD) + h * VD;
        #pragma unroll
        for (int vt = 0; vt < 8; ++vt)
            op[vt * 16 + n] = Oa[vt][r] * inv;
    }
}

extern "C" void kernel_launch(void* const* d_in, const int* in_sizes, int n_in,
                              void* d_out, int out_size, void* d_ws, size_t ws_size,
                              hipStream_t stream)
{
    const float* x         = (const float*)d_in[0];
    const float* Wq        = (const float*)d_in[1];
    const float* Wkv_a     = (const float*)d_in[2];
    const float* kv_norm_w = (const float*)d_in[3];
    const float* Wkv_b     = (const float*)d_in[4];
    const float* Wo        = (const float*)d_in[5];
    float* out = (float*)d_out;

    float* ws = (float*)d_ws;
    float* q_raw  = ws;                                   // 12,582,912 f
    float* kv_a   = q_raw + (size_t)12582912;             //  2,359,296 f
    float* kv_b   = kv_a  + (size_t)2359296;              // 16,777,216 f
    float* attn_o = kv_b;                                 // alias: kv_b dead during attention
    __bf16* Kb = (__bf16*)(kv_b + (size_t)16777216);      // 12,582,912 bf16
    __bf16* Vt = (__bf16*)(kv_b + (size_t)16777216 + 6291456); // 8,388,608 bf16

    const int M = BATCH * SEQ;   // 4096
    dim3 blk(256);

    gemm_f32<<<dim3(3072 / 64, M / 64), blk, 0, stream>>>(x, Wq, q_raw, DM, DM, NH * QKD, NH * QKD);
    gemm_f32<<<dim3(576 / 64, M / 64), blk, 0, stream>>>(x, Wkv_a, kv_a, DM, DM, KVL + QKR, KVL + QKR);
    rope_q_kernel<<<(BATCH * SEQ * NH * 32) / 256, blk, 0, stream>>>(q_raw);
    rope_k_kernel<<<(BATCH * SEQ * 32) / 256, blk, 0, stream>>>(kv_a);
    rmsnorm_kernel<<<M, blk, 0, stream>>>(kv_a, kv_norm_w);
    gemm_f32<<<dim3(4096 / 64, M / 64), blk, 0, stream>>>(kv_a, Wkv_b, kv_b, KVL, KVL + QKR, NH * 256, NH * 256);
    build_k<<<(BATCH * NH * SEQ * QKD) / 256, blk, 0, stream>>>(kv_b, kv_a, Kb);
    build_vt<<<dim3(SEQ / 64, NH, BATCH), blk, 0, stream>>>(kv_b, Vt);
    attn_mfma<<<dim3(SEQ / 64, NH, BATCH), blk, 0, stream>>>(q_raw, Kb, Vt, attn_o);
    gemm_f32<<<dim3(2048 / 64, M / 64), blk, 0, stream>>>(attn_o, Wo, out, NH * VD, NH * VD, DM, DM);
}

// Round 3
// 594.318 us; speedup vs baseline: 23.3679x; 3.5386x over previous
//
#include <hip/hip_runtime.h>
#include <hip/hip_bf16.h>
#include <math.h>

#define BATCH   2
#define SEQ     2048
#define DM      2048
#define NH      16
#define QKR     64
#define QKN     128
#define KVL     512
#define VD      128
#define QKD     192     // QKN + QKR
#define KVA_LD  640     // padded row stride of kv_a (576 -> 640 for 128-tile GEMM)
#define RMS_EPS 1.1920928955078125e-07f

typedef __bf16 bf16x8 __attribute__((ext_vector_type(8)));
typedef float  f32x4  __attribute__((ext_vector_type(4)));

// ---- async global->LDS 16B copy (wave-uniform base + lane*16 dest semantics) ----
__device__ __forceinline__ void async16(const __bf16* g, __bf16* l)
{
    __builtin_amdgcn_global_load_lds(
        (__attribute__((address_space(1))) unsigned int*)g,
        (__attribute__((address_space(3))) unsigned int*)l,
        16, 0, 0);
}

// ---------------- fp32 [n] -> bf16 [n] ----------------
__global__ __launch_bounds__(256) void f32_to_bf16(const float* __restrict__ src,
                                                   __bf16* __restrict__ dst)
{
    int i = (blockIdx.x * 256 + threadIdx.x) * 4;
    float4 v = *reinterpret_cast<const float4*>(src + i);
    dst[i + 0] = (__bf16)v.x;
    dst[i + 1] = (__bf16)v.y;
    dst[i + 2] = (__bf16)v.z;
    dst[i + 3] = (__bf16)v.w;
}

// ---------------- W fp32 [K,N] -> W^T bf16 [Nout,K], zero-pad rows n>=N ----------------
// grid = (Nout/64, K/64), block 256
__global__ __launch_bounds__(256) void transpose_w(const float* __restrict__ W,
                                                   __bf16* __restrict__ Wt,
                                                   int K, int N)
{
    __shared__ float t[64][65];
    const int n0 = blockIdx.x * 64, k0 = blockIdx.y * 64;
    const int tid = threadIdx.x;
    #pragma unroll
    for (int i = 0; i < 16; ++i) {
        int flat = i * 256 + tid;          // 0..4095
        int kl = flat >> 6, nl = flat & 63;
        t[kl][nl] = (n0 + nl < N) ? W[(size_t)(k0 + kl) * N + n0 + nl] : 0.f;
    }
    __syncthreads();
    #pragma unroll
    for (int i = 0; i < 16; ++i) {
        int flat = i * 256 + tid;
        int nl = flat >> 6, kl = flat & 63;
        Wt[(size_t)(n0 + nl) * K + k0 + kl] = (__bf16)t[kl][nl];
    }
}

// ---------------- bf16 MFMA GEMM: C[M,N] = A[M,K] @ Bt[N,K]^T ----------------
// grid = (N/128, M/128), block 256 (4 waves, each a 64x64 quadrant)
template<typename OT>
__global__ __launch_bounds__(256) void gemm_bf16(const __bf16* __restrict__ A,
                                                 const __bf16* __restrict__ Bt,
                                                 OT* __restrict__ C,
                                                 int K, int lda, int ldb, int ldc)
{
    __shared__ __bf16 As[128 * 32];
    __shared__ __bf16 Bs[128 * 32];
    const int tid = threadIdx.x;
    const int lane = tid & 63, wave = tid >> 6;
    const int n = lane & 15, quad = lane >> 4;
    const int row0 = blockIdx.y * 128, col0 = blockIdx.x * 128;
    const int wm = (wave >> 1) * 64, wn = (wave & 1) * 64;

    f32x4 acc[4][4];
    #pragma unroll
    for (int mi = 0; mi < 4; ++mi)
        #pragma unroll
        for (int ni = 0; ni < 4; ++ni)
            #pragma unroll
            for (int r = 0; r < 4; ++r) acc[mi][ni][r] = 0.f;

    // staging: chunk c = {tid, tid+256}; row = c>>2, 8-elem colchunk = c&3
    const __bf16* Ag0 = A  + (size_t)(row0 + (tid >> 2)) * lda + (tid & 3) * 8;
    const __bf16* Bg0 = Bt + (size_t)(col0 + (tid >> 2)) * ldb + (tid & 3) * 8;
    const __bf16* Ag1 = Ag0 + (size_t)64 * lda;
    const __bf16* Bg1 = Bg0 + (size_t)64 * ldb;
    __bf16* As0 = As + tid * 8;        __bf16* As1 = As + (tid + 256) * 8;
    __bf16* Bs0 = Bs + tid * 8;        __bf16* Bs1 = Bs + (tid + 256) * 8;

    for (int k0 = 0; k0 < K; k0 += 32) {
        __syncthreads();
        async16(Ag0 + k0, As0);
        async16(Ag1 + k0, As1);
        async16(Bg0 + k0, Bs0);
        async16(Bg1 + k0, Bs1);
        __syncthreads();

        bf16x8 af[4], bfr[4];
        #pragma unroll
        for (int mi = 0; mi < 4; ++mi)
            af[mi] = *reinterpret_cast<const bf16x8*>(&As[(wm + mi * 16 + n) * 32 + quad * 8]);
        #pragma unroll
        for (int ni = 0; ni < 4; ++ni)
            bfr[ni] = *reinterpret_cast<const bf16x8*>(&Bs[(wn + ni * 16 + n) * 32 + quad * 8]);
        #pragma unroll
        for (int mi = 0; mi < 4; ++mi)
            #pragma unroll
            for (int ni = 0; ni < 4; ++ni)
                acc[mi][ni] = __builtin_amdgcn_mfma_f32_16x16x32_bf16(af[mi], bfr[ni], acc[mi][ni], 0, 0, 0);
    }

    #pragma unroll
    for (int mi = 0; mi < 4; ++mi)
        #pragma unroll
        for (int r = 0; r < 4; ++r) {
            OT* cp = C + (size_t)(row0 + wm + mi * 16 + quad * 4 + r) * ldc + col0 + wn + n;
            #pragma unroll
            for (int ni = 0; ni < 4; ++ni)
                cp[ni * 16] = (OT)acc[mi][ni][r];
        }
}

// ---------------- RoPE on q (bf16, in-place), fp32 math ----------------
__global__ __launch_bounds__(256) void rope_q_kernel(__bf16* __restrict__ q)
{
    int idx = blockIdx.x * 256 + threadIdx.x;   // B*S*NH*32
    int i = idx & 31;
    int h = (idx >> 5) & 15;
    int s = (idx >> 9) & 2047;
    int b = idx >> 20;
    float t = (float)s * __expf(-(float)(2 * i) / 64.0f * 9.210340371976184f); // ln(10000)
    float c = __cosf(t), sn = __sinf(t);
    __bf16* p = q + ((size_t)(b * SEQ + s)) * (NH * QKD) + h * QKD + QKN + 2 * i;
    float x1 = (float)p[0], x2 = (float)p[1];
    p[0] = (__bf16)(x1 * c - x2 * sn);
    p[1] = (__bf16)(x2 * c + x1 * sn);
}

// ---------------- RoPE on k_rope (fp32 kv_a cols [512,576), stride 640) ----------------
__global__ __launch_bounds__(256) void rope_k_kernel(float* __restrict__ kva)
{
    int idx = blockIdx.x * 256 + threadIdx.x;   // B*S*32
    int i = idx & 31;
    int s = (idx >> 5) & 2047;
    int b = idx >> 16;
    float t = (float)s * __expf(-(float)(2 * i) / 64.0f * 9.210340371976184f);
    float c = __cosf(t), sn = __sinf(t);
    float* p = kva + ((size_t)(b * SEQ + s)) * KVA_LD + KVL + 2 * i;
    float x1 = p[0], x2 = p[1];
    p[0] = x1 * c - x2 * sn;
    p[1] = x2 * c + x1 * sn;
}

// ---------------- RMSNorm c_kv (fp32 in, stride 640) -> bf16 out [4096,512] ----------------
__global__ __launch_bounds__(256) void rmsnorm_kernel(const float* __restrict__ kva,
                                                      const float* __restrict__ w,
                                                      __bf16* __restrict__ out)
{
    const int rid = blockIdx.x;
    const float* row = kva + (size_t)rid * KVA_LD;
    const int tid = threadIdx.x;
    float v[2];
    float ss = 0.f;
    #pragma unroll
    for (int j = 0; j < 2; ++j) {
        int d = tid + j * 256;
        v[j] = row[d];
        ss += v[j] * v[j];
    }
    #pragma unroll
    for (int off = 32; off > 0; off >>= 1) ss += __shfl_down(ss, off, 64);
    __shared__ float red[4];
    if ((tid & 63) == 0) red[tid >> 6] = ss;
    __syncthreads();
    float total = red[0] + red[1] + red[2] + red[3];
    float scale = 1.0f / sqrtf(total * (1.0f / KVL) + RMS_EPS);
    #pragma unroll
    for (int j = 0; j < 2; ++j) {
        int d = tid + j * 256;
        out[(size_t)rid * KVL + d] = (__bf16)(v[j] * scale * w[d]);
    }
}

// ---------------- build bf16 K = [nope | rope] : [B,H,S,192] ----------------
__global__ __launch_bounds__(256) void build_k(const __bf16* __restrict__ kvb,
                                               const float* __restrict__ kva,
                                               __bf16* __restrict__ Kb)
{
    int idx = blockIdx.x * 256 + threadIdx.x;       // B*H*S*192
    int d = idx % 192;
    int s = (idx / 192) & 2047;
    int hb = idx / (192 * 2048);
    int h = hb & 15, b = hb >> 4;
    __bf16 v;
    if (d < 128) v = kvb[((size_t)(b * SEQ + s)) * (NH * 256) + h * 256 + d];
    else         v = (__bf16)kva[((size_t)(b * SEQ + s)) * KVA_LD + KVL + (d - 128)];
    Kb[idx] = v;
}

// ---------------- build bf16 V^T : [B,H,128,S] from bf16 kv_b ----------------
__global__ __launch_bounds__(256) void build_vt(const __bf16* __restrict__ kvb,
                                                __bf16* __restrict__ Vt)
{
    __shared__ __bf16 tile[64][136];
    const int s0 = blockIdx.x * 64, h = blockIdx.y, b = blockIdx.z;
    const int t = threadIdx.x;
    #pragma unroll
    for (int i = 0; i < 4; ++i) {
        int flat = i * 256 + t;                     // 1024 chunks: 64 rows x 16 chunks
        int sl = flat >> 4, c8 = flat & 15;
        bf16x8 v = *reinterpret_cast<const bf16x8*>(
            &kvb[((size_t)(b * SEQ + s0 + sl)) * (NH * 256) + h * 256 + 128 + c8 * 8]);
        *reinterpret_cast<bf16x8*>(&tile[sl][c8 * 8]) = v;
    }
    __syncthreads();
    #pragma unroll
    for (int j = 0; j < 32; ++j) {
        int flat = j * 256 + t;                     // 8192: 128 d x 64 s
        int d = flat >> 6, sl = flat & 63;
        Vt[((size_t)((b * NH + h) * VD + d)) * SEQ + s0 + sl] = tile[sl][d];
    }
}

// ---------------- MFMA flash attention ----------------
// qb: [B,S,NH*192] bf16 (rope applied); Kb: [B,H,S,192] bf16; Vt: [B,H,128,S] bf16
// ob: [B,S,NH*128] bf16
#define LKS 200   // 192 + 8 pad
#define LVS 72    // 64 + 8
#define LPS 72
__global__ __launch_bounds__(256) void attn_mfma(const __bf16* __restrict__ qb,
                                                 const __bf16* __restrict__ Kb,
                                                 const __bf16* __restrict__ Vt,
                                                 __bf16* __restrict__ ob)
{
    __shared__ __bf16 Ks[64 * LKS];
    __shared__ __bf16 Vs[128 * LVS];
    __shared__ __bf16 Ps[4 * 16 * LPS];
    const int tid = threadIdx.x;
    const int wave = tid >> 6, lane = tid & 63;
    const int n = lane & 15, quad = lane >> 4;
    const int qt = blockIdx.x, h = blockIdx.y, b = blockIdx.z;
    const int q0 = qt * 64;
    const int bh = b * NH + h;
    const float scale = 0.07216878364870323f;   // 1/sqrt(192)

    bf16x8 qfrag[6];
    const int qrow = q0 + wave * 16 + n;
    const __bf16* qp = qb + ((size_t)(b * SEQ + qrow)) * (NH * QKD) + h * QKD + quad * 8;
    #pragma unroll
    for (int c = 0; c < 6; ++c)
        qfrag[c] = *reinterpret_cast<const bf16x8*>(qp + c * 32);

    f32x4 Oa[8];
    #pragma unroll
    for (int i = 0; i < 8; ++i)
        #pragma unroll
        for (int r = 0; r < 4; ++r) Oa[i][r] = 0.f;
    float m_i[4], l_i[4];
    #pragma unroll
    for (int r = 0; r < 4; ++r) { m_i[r] = -1e30f; l_i[r] = 0.f; }

    const __bf16* Kg = Kb + (size_t)bh * SEQ * QKD;
    const __bf16* Vg = Vt + (size_t)bh * VD * SEQ;
    const int ntiles = qt + 1;

    for (int kt = 0; kt < ntiles; ++kt) {
        const int k0 = kt * 64;
        __syncthreads();
        #pragma unroll
        for (int i = 0; i < 6; ++i) {
            int flat = i * 256 + tid;
            int key = flat / 24, c8 = flat % 24;
            bf16x8 v = *reinterpret_cast<const bf16x8*>(Kg + (size_t)(k0 + key) * QKD + c8 * 8);
            *reinterpret_cast<bf16x8*>(&Ks[key * LKS + c8 * 8]) = v;
        }
        #pragma unroll
        for (int i = 0; i < 4; ++i) {
            int flat = i * 256 + tid;
            int d = flat >> 3, c8 = flat & 7;
            bf16x8 v = *reinterpret_cast<const bf16x8*>(Vg + (size_t)d * SEQ + k0 + c8 * 8);
            *reinterpret_cast<bf16x8*>(&Vs[d * LVS + c8 * 8]) = v;
        }
        __syncthreads();

        f32x4 sacc[4];
        #pragma unroll
        for (int t = 0; t < 4; ++t) {
            f32x4 a;
            #pragma unroll
            for (int r = 0; r < 4; ++r) a[r] = 0.f;
            #pragma unroll
            for (int c = 0; c < 6; ++c) {
                bf16x8 kf = *reinterpret_cast<const bf16x8*>(&Ks[(t * 16 + n) * LKS + c * 32 + quad * 8]);
                a = __builtin_amdgcn_mfma_f32_16x16x32_bf16(qfrag[c], kf, a, 0, 0, 0);
            }
            sacc[t] = a;
        }

        const int qg = q0 + wave * 16 + quad * 4;
        float mloc[4];
        #pragma unroll
        for (int r = 0; r < 4; ++r) mloc[r] = -1e30f;
        #pragma unroll
        for (int t = 0; t < 4; ++t) {
            int key = k0 + t * 16 + n;
            #pragma unroll
            for (int r = 0; r < 4; ++r) {
                float s = sacc[t][r] * scale;
                s = (key <= qg + r) ? s : -1e30f;
                sacc[t][r] = s;
                mloc[r] = fmaxf(mloc[r], s);
            }
        }
        #pragma unroll
        for (int off = 1; off < 16; off <<= 1)
            #pragma unroll
            for (int r = 0; r < 4; ++r)
                mloc[r] = fmaxf(mloc[r], __shfl_xor(mloc[r], off, 64));
        float alpha[4], sum[4];
        #pragma unroll
        for (int r = 0; r < 4; ++r) {
            float mn = fmaxf(m_i[r], mloc[r]);
            alpha[r] = __expf(m_i[r] - mn);
            m_i[r] = mn;
            sum[r] = 0.f;
        }
        #pragma unroll
        for (int t = 0; t < 4; ++t)
            #pragma unroll
            for (int r = 0; r < 4; ++r) {
                float p = __expf(sacc[t][r] - m_i[r]);
                sum[r] += p;
                Ps[wave * 16 * LPS + (quad * 4 + r) * LPS + t * 16 + n] = (__bf16)p;
            }
        #pragma unroll
        for (int off = 1; off < 16; off <<= 1)
            #pragma unroll
            for (int r = 0; r < 4; ++r)
                sum[r] += __shfl_xor(sum[r], off, 64);
        #pragma unroll
        for (int r = 0; r < 4; ++r) l_i[r] = l_i[r] * alpha[r] + sum[r];
        #pragma unroll
        for (int i = 0; i < 8; ++i)
            #pragma unroll
            for (int r = 0; r < 4; ++r) Oa[i][r] *= alpha[r];

        __asm__ volatile("s_waitcnt lgkmcnt(0)" ::: "memory");

        #pragma unroll
        for (int kc = 0; kc < 2; ++kc) {
            bf16x8 pf = *reinterpret_cast<const bf16x8*>(&Ps[wave * 16 * LPS + n * LPS + kc * 32 + quad * 8]);
            #pragma unroll
            for (int vt = 0; vt < 8; ++vt) {
                bf16x8 vf = *reinterpret_cast<const bf16x8*>(&Vs[(vt * 16 + n) * LVS + kc * 32 + quad * 8]);
                Oa[vt] = __builtin_amdgcn_mfma_f32_16x16x32_bf16(pf, vf, Oa[vt], 0, 0, 0);
            }
        }
    }

    #pragma unroll
    for (int r = 0; r < 4; ++r) {
        float inv = 1.0f / l_i[r];
        int row = q0 + wave * 16 + quad * 4 + r;
        __bf16* op = ob + ((size_t)(b * SEQ + row)) * (NH * VD) + h * VD;
        #pragma unroll
        for (int vt = 0; vt < 8; ++vt)
            op[vt * 16 + n] = (__bf16)(Oa[vt][r] * inv);
    }
}

extern "C" void kernel_launch(void* const* d_in, const int* in_sizes, int n_in,
                              void* d_out, int out_size, void* d_ws, size_t ws_size,
                              hipStream_t stream)
{
    const float* x         = (const float*)d_in[0];
    const float* Wq        = (const float*)d_in[1];
    const float* Wkv_a     = (const float*)d_in[2];
    const float* kv_norm_w = (const float*)d_in[3];
    const float* Wkv_b     = (const float*)d_in[4];
    const float* Wo        = (const float*)d_in[5];
    float* out = (float*)d_out;

    // workspace layout (f32-unit offsets); aliasing noted
    float* ws = (float*)d_ws;
    __bf16* q_bf   = (__bf16*)ws;                              // 12,582,912 bf16 (6,291,456 f)
    float*  kv_a   = ws + 6291456;                             // 4096x640 f32 (2,621,440 f)
    __bf16* kv_b   = (__bf16*)(ws + 8912896);                  // 16,777,216 bf16 (8,388,608 f)
    __bf16* attn_o = kv_b;                                     // alias: kv_b dead after build_vt
    float*  r3     = ws + 17301504;                            // 16MB: xb then Vt
    __bf16* xb     = (__bf16*)r3;                              // 8,388,608 bf16
    __bf16* Vt     = (__bf16*)r3;                              // 8,388,608 bf16 (alias, later)
    float*  r4     = ws + 21495808;                            // 24MB: weights then Kb
    __bf16* Wq_t   = (__bf16*)r4;                              // 6,291,456 bf16
    __bf16* Wkva_t = (__bf16*)(r4 + 3145728);                  // 1,310,720 bf16 (640x2048)
    __bf16* Wkvb_t = (__bf16*)(r4 + 3801088);                  // 2,097,152 bf16
    __bf16* Kb     = (__bf16*)r4;                              // 12,582,912 bf16 (alias, later)
    __bf16* Wo_t   = (__bf16*)(ws + 27787264);                 // 4,194,304 bf16
    __bf16* c_kv_n = (__bf16*)(ws + 29884416);                 // 2,097,152 bf16
    // total: 30,932,992 f = 123.7 MB

    const int M = BATCH * SEQ;   // 4096
    dim3 blk(256);

    // casts + weight transposes
    f32_to_bf16<<<(M * DM) / 1024, blk, 0, stream>>>(x, xb);
    transpose_w<<<dim3(3072 / 64, 2048 / 64), blk, 0, stream>>>(Wq, Wq_t, DM, NH * QKD);
    transpose_w<<<dim3(640 / 64, 2048 / 64), blk, 0, stream>>>(Wkv_a, Wkva_t, DM, KVL + QKR);
    transpose_w<<<dim3(4096 / 64, 512 / 64), blk, 0, stream>>>(Wkv_b, Wkvb_t, KVL, NH * 256);
    transpose_w<<<dim3(2048 / 64, 2048 / 64), blk, 0, stream>>>(Wo, Wo_t, NH * VD, DM);

    // q = x @ Wq  -> bf16 [4096,3072]
    gemm_bf16<__bf16><<<dim3(3072 / 128, M / 128), blk, 0, stream>>>(xb, Wq_t, q_bf, DM, DM, DM, NH * QKD);
    // kv_a = x @ Wkv_a -> fp32 [4096,640] (cols 576.. are zeros)
    gemm_bf16<float><<<dim3(640 / 128, M / 128), blk, 0, stream>>>(xb, Wkva_t, kv_a, DM, DM, DM, KVA_LD);

    rope_q_kernel<<<(BATCH * SEQ * NH * 32) / 256, blk, 0, stream>>>(q_bf);
    rope_k_kernel<<<(BATCH * SEQ * 32) / 256, blk, 0, stream>>>(kv_a);
    rmsnorm_kernel<<<M, blk, 0, stream>>>(kv_a, kv_norm_w, c_kv_n);

    // kv_b = c_kv_n @ Wkv_b -> bf16 [4096,4096]
    gemm_bf16<__bf16><<<dim3(4096 / 128, M / 128), blk, 0, stream>>>(c_kv_n, Wkvb_t, kv_b, KVL, KVL, KVL, NH * 256);

    build_k<<<(BATCH * NH * SEQ * QKD) / 256, blk, 0, stream>>>(kv_b, kv_a, Kb);
    build_vt<<<dim3(SEQ / 64, NH, BATCH), blk, 0, stream>>>(kv_b, Vt);

    attn_mfma<<<dim3(SEQ / 64, NH, BATCH), blk, 0, stream>>>(q_bf, Kb, Vt, attn_o);

    // out = attn_o @ Wo -> fp32 [4096,2048]
    gemm_bf16<float><<<dim3(2048 / 128, M / 128), blk, 0, stream>>>(attn_o, Wo_t, out, NH * VD, NH * VD, NH * VD, DM);
}

// Round 4
// 535.886 us; speedup vs baseline: 25.9159x; 1.1090x over previous
//
#include <hip/hip_runtime.h>
#include <hip/hip_bf16.h>
#include <math.h>

#define BATCH   2
#define SEQ     2048
#define DM      2048
#define NH      16
#define QKR     64
#define QKN     128
#define KVL     512
#define VD      128
#define QKD     192     // QKN + QKR
#define KVA_LD  640     // padded row stride of kv_a (576 -> 640 for 128-tile GEMM)
#define RMS_EPS 1.1920928955078125e-07f

typedef __bf16 bf16x8 __attribute__((ext_vector_type(8)));
typedef float  f32x4  __attribute__((ext_vector_type(4)));

// ---- async global->LDS 16B copy (wave-uniform base + lane*16 dest semantics) ----
__device__ __forceinline__ void async16(const __bf16* g, __bf16* l)
{
    __builtin_amdgcn_global_load_lds(
        (__attribute__((address_space(1))) unsigned int*)g,
        (__attribute__((address_space(3))) unsigned int*)l,
        16, 0, 0);
}

// ---------------- fp32 [n] -> bf16 [n] ----------------
__global__ __launch_bounds__(256) void f32_to_bf16(const float* __restrict__ src,
                                                   __bf16* __restrict__ dst)
{
    int i = (blockIdx.x * 256 + threadIdx.x) * 4;
    float4 v = *reinterpret_cast<const float4*>(src + i);
    dst[i + 0] = (__bf16)v.x;
    dst[i + 1] = (__bf16)v.y;
    dst[i + 2] = (__bf16)v.z;
    dst[i + 3] = (__bf16)v.w;
}

// ---------------- W fp32 [K,N] -> W^T bf16 [Nout,K], zero-pad rows n>=N ----------------
__global__ __launch_bounds__(256) void transpose_w(const float* __restrict__ W,
                                                   __bf16* __restrict__ Wt,
                                                   int K, int N)
{
    __shared__ float t[64][65];
    const int n0 = blockIdx.x * 64, k0 = blockIdx.y * 64;
    const int tid = threadIdx.x;
    #pragma unroll
    for (int i = 0; i < 16; ++i) {
        int flat = i * 256 + tid;
        int kl = flat >> 6, nl = flat & 63;
        t[kl][nl] = (n0 + nl < N) ? W[(size_t)(k0 + kl) * N + n0 + nl] : 0.f;
    }
    __syncthreads();
    #pragma unroll
    for (int i = 0; i < 16; ++i) {
        int flat = i * 256 + tid;
        int nl = flat >> 6, kl = flat & 63;
        Wt[(size_t)(n0 + nl) * K + k0 + kl] = (__bf16)t[kl][nl];
    }
}

// ---------------- bf16 MFMA GEMM: C[M,N] = A[M,K] @ Bt[N,K]^T ----------------
template<typename OT>
__global__ __launch_bounds__(256) void gemm_bf16(const __bf16* __restrict__ A,
                                                 const __bf16* __restrict__ Bt,
                                                 OT* __restrict__ C,
                                                 int K, int lda, int ldb, int ldc)
{
    __shared__ __bf16 As[128 * 32];
    __shared__ __bf16 Bs[128 * 32];
    const int tid = threadIdx.x;
    const int lane = tid & 63, wave = tid >> 6;
    const int n = lane & 15, quad = lane >> 4;
    const int row0 = blockIdx.y * 128, col0 = blockIdx.x * 128;
    const int wm = (wave >> 1) * 64, wn = (wave & 1) * 64;

    f32x4 acc[4][4];
    #pragma unroll
    for (int mi = 0; mi < 4; ++mi)
        #pragma unroll
        for (int ni = 0; ni < 4; ++ni)
            #pragma unroll
            for (int r = 0; r < 4; ++r) acc[mi][ni][r] = 0.f;

    const __bf16* Ag0 = A  + (size_t)(row0 + (tid >> 2)) * lda + (tid & 3) * 8;
    const __bf16* Bg0 = Bt + (size_t)(col0 + (tid >> 2)) * ldb + (tid & 3) * 8;
    const __bf16* Ag1 = Ag0 + (size_t)64 * lda;
    const __bf16* Bg1 = Bg0 + (size_t)64 * ldb;
    __bf16* As0 = As + tid * 8;        __bf16* As1 = As + (tid + 256) * 8;
    __bf16* Bs0 = Bs + tid * 8;        __bf16* Bs1 = Bs + (tid + 256) * 8;

    for (int k0 = 0; k0 < K; k0 += 32) {
        __syncthreads();
        async16(Ag0 + k0, As0);
        async16(Ag1 + k0, As1);
        async16(Bg0 + k0, Bs0);
        async16(Bg1 + k0, Bs1);
        __syncthreads();

        bf16x8 af[4], bfr[4];
        #pragma unroll
        for (int mi = 0; mi < 4; ++mi)
            af[mi] = *reinterpret_cast<const bf16x8*>(&As[(wm + mi * 16 + n) * 32 + quad * 8]);
        #pragma unroll
        for (int ni = 0; ni < 4; ++ni)
            bfr[ni] = *reinterpret_cast<const bf16x8*>(&Bs[(wn + ni * 16 + n) * 32 + quad * 8]);
        #pragma unroll
        for (int mi = 0; mi < 4; ++mi)
            #pragma unroll
            for (int ni = 0; ni < 4; ++ni)
                acc[mi][ni] = __builtin_amdgcn_mfma_f32_16x16x32_bf16(af[mi], bfr[ni], acc[mi][ni], 0, 0, 0);
    }

    #pragma unroll
    for (int mi = 0; mi < 4; ++mi)
        #pragma unroll
        for (int r = 0; r < 4; ++r) {
            OT* cp = C + (size_t)(row0 + wm + mi * 16 + quad * 4 + r) * ldc + col0 + wn + n;
            #pragma unroll
            for (int ni = 0; ni < 4; ++ni)
                cp[ni * 16] = (OT)acc[mi][ni][r];
        }
}

// ---------------- RoPE on q (bf16, in-place), fp32 math ----------------
__global__ __launch_bounds__(256) void rope_q_kernel(__bf16* __restrict__ q)
{
    int idx = blockIdx.x * 256 + threadIdx.x;   // B*S*NH*32
    int i = idx & 31;
    int h = (idx >> 5) & 15;
    int s = (idx >> 9) & 2047;
    int b = idx >> 20;
    float t = (float)s * __expf(-(float)(2 * i) / 64.0f * 9.210340371976184f); // ln(10000)
    float c = __cosf(t), sn = __sinf(t);
    __bf16* p = q + ((size_t)(b * SEQ + s)) * (NH * QKD) + h * QKD + QKN + 2 * i;
    float x1 = (float)p[0], x2 = (float)p[1];
    p[0] = (__bf16)(x1 * c - x2 * sn);
    p[1] = (__bf16)(x2 * c + x1 * sn);
}

// ---------------- RoPE on k_rope: kv_a fp32 cols [512,576) -> bf16 krope [B,S,64] ----------------
__global__ __launch_bounds__(256) void rope_k_kernel(const float* __restrict__ kva,
                                                     __bf16* __restrict__ krope)
{
    int idx = blockIdx.x * 256 + threadIdx.x;   // B*S*32
    int i = idx & 31;
    int s = (idx >> 5) & 2047;
    int b = idx >> 16;
    float t = (float)s * __expf(-(float)(2 * i) / 64.0f * 9.210340371976184f);
    float c = __cosf(t), sn = __sinf(t);
    const float* p = kva + ((size_t)(b * SEQ + s)) * KVA_LD + KVL + 2 * i;
    float x1 = p[0], x2 = p[1];
    __bf16* o = krope + ((size_t)(b * SEQ + s)) * QKR + 2 * i;
    o[0] = (__bf16)(x1 * c - x2 * sn);
    o[1] = (__bf16)(x2 * c + x1 * sn);
}

// ---------------- RMSNorm c_kv (fp32 in, stride 640) -> bf16 out [4096,512] ----------------
__global__ __launch_bounds__(256) void rmsnorm_kernel(const float* __restrict__ kva,
                                                      const float* __restrict__ w,
                                                      __bf16* __restrict__ out)
{
    const int rid = blockIdx.x;
    const float* row = kva + (size_t)rid * KVA_LD;
    const int tid = threadIdx.x;
    float v[2];
    float ss = 0.f;
    #pragma unroll
    for (int j = 0; j < 2; ++j) {
        int d = tid + j * 256;
        v[j] = row[d];
        ss += v[j] * v[j];
    }
    #pragma unroll
    for (int off = 32; off > 0; off >>= 1) ss += __shfl_down(ss, off, 64);
    __shared__ float red[4];
    if ((tid & 63) == 0) red[tid >> 6] = ss;
    __syncthreads();
    float total = red[0] + red[1] + red[2] + red[3];
    float scale = 1.0f / sqrtf(total * (1.0f / KVL) + RMS_EPS);
    #pragma unroll
    for (int j = 0; j < 2; ++j) {
        int d = tid + j * 256;
        out[(size_t)rid * KVL + d] = (__bf16)(v[j] * scale * w[d]);
    }
}

// ---------------- build bf16 V^T : [B,H,128,S] from bf16 kv_b ----------------
__global__ __launch_bounds__(256) void build_vt(const __bf16* __restrict__ kvb,
                                                __bf16* __restrict__ Vt)
{
    __shared__ __bf16 tile[64][136];
    const int s0 = blockIdx.x * 64, h = blockIdx.y, b = blockIdx.z;
    const int t = threadIdx.x;
    #pragma unroll
    for (int i = 0; i < 4; ++i) {
        int flat = i * 256 + t;
        int sl = flat >> 4, c8 = flat & 15;
        bf16x8 v = *reinterpret_cast<const bf16x8*>(
            &kvb[((size_t)(b * SEQ + s0 + sl)) * (NH * 256) + h * 256 + 128 + c8 * 8]);
        *reinterpret_cast<bf16x8*>(&tile[sl][c8 * 8]) = v;
    }
    __syncthreads();
    #pragma unroll
    for (int j = 0; j < 32; ++j) {
        int flat = j * 256 + t;
        int d = flat >> 6, sl = flat & 63;
        Vt[((size_t)((b * NH + h) * VD + d)) * SEQ + s0 + sl] = tile[sl][d];
    }
}

// ---------------- MFMA flash attention, paired q-strips ----------------
// qb: [B,S,NH*192] bf16 (rope applied); kvb: [B,S,NH*256] bf16 (k_nope|v);
// krope: [B,S,64] bf16; Vt: [B,H,128,S] bf16; ob: [B,S,NH*128] bf16
// Block = pair p: strips qs0=p (k-tiles 0..p) and qs1=31-p (k-tiles 0..31-p).
// Uniform 33 strip-tile computes per block; 512 blocks, all co-resident.
#define LKS 216   // 192 + 24 pad
#define LVS 72    // 64 + 8
#define LPS 72
__global__ __launch_bounds__(256, 2) void attn_mfma(const __bf16* __restrict__ qb,
                                                    const __bf16* __restrict__ kvb,
                                                    const __bf16* __restrict__ krope,
                                                    const __bf16* __restrict__ Vt,
                                                    __bf16* __restrict__ ob)
{
    __shared__ __bf16 Ks[64 * LKS];        // 27648 B
    __shared__ __bf16 Vs[128 * LVS];       // 18432 B
    __shared__ __bf16 Ps[2][4 * 16 * LPS]; // 18432 B   (total 64512 B)
    const int tid = threadIdx.x;
    const int wave = tid >> 6, lane = tid & 63;
    const int n = lane & 15, quad = lane >> 4;
    const int pair = blockIdx.x, h = blockIdx.y, b = blockIdx.z;
    const int bh = b * NH + h;
    const float scale = 0.07216878364870323f;   // 1/sqrt(192)
    int qs[2];
    qs[0] = pair; qs[1] = 31 - pair;
    const int ntmax = qs[1] + 1;

    // Q fragments for both strips (A-layout: m=n, k=quad*8+j)
    bf16x8 qfrag[2][6];
    #pragma unroll
    for (int s = 0; s < 2; ++s) {
        const int qrow = qs[s] * 64 + wave * 16 + n;
        const __bf16* qp = qb + ((size_t)(b * SEQ + qrow)) * (NH * QKD) + h * QKD + quad * 8;
        #pragma unroll
        for (int c = 0; c < 6; ++c)
            qfrag[s][c] = *reinterpret_cast<const bf16x8*>(qp + c * 32);
    }

    f32x4 Oa[2][8];
    float m_i[2][4], l_i[2][4];
    #pragma unroll
    for (int s = 0; s < 2; ++s) {
        #pragma unroll
        for (int i = 0; i < 8; ++i)
            #pragma unroll
            for (int r = 0; r < 4; ++r) Oa[s][i][r] = 0.f;
        #pragma unroll
        for (int r = 0; r < 4; ++r) { m_i[s][r] = -1e30f; l_i[s][r] = 0.f; }
    }

    // per-thread staging coordinates
    int kkey[6], kc8[6];
    #pragma unroll
    for (int i = 0; i < 6; ++i) {
        int flat = i * 256 + tid;
        kkey[i] = flat / 24; kc8[i] = flat % 24;
    }
    const int vd = tid >> 3, vc8 = tid & 7;     // flat = i*256+tid -> d = vd + i*32

    const __bf16* Vg = Vt + (size_t)bh * VD * SEQ;

    bf16x8 kpre[6], vpre[4];
    // prefetch tile 0
    {
        const int k0 = 0;
        #pragma unroll
        for (int i = 0; i < 6; ++i) {
            const __bf16* src = (kc8[i] < 16)
                ? kvb + ((size_t)(b * SEQ + k0 + kkey[i])) * (NH * 256) + h * 256 + kc8[i] * 8
                : krope + ((size_t)(b * SEQ + k0 + kkey[i])) * QKR + (kc8[i] - 16) * 8;
            kpre[i] = *reinterpret_cast<const bf16x8*>(src);
        }
        #pragma unroll
        for (int i = 0; i < 4; ++i)
            vpre[i] = *reinterpret_cast<const bf16x8*>(Vg + (size_t)(vd + i * 32) * SEQ + k0 + vc8 * 8);
    }

    for (int kt = 0; kt < ntmax; ++kt) {
        __syncthreads();   // previous iteration's compute done; Ks/Vs safe to overwrite
        #pragma unroll
        for (int i = 0; i < 6; ++i)
            *reinterpret_cast<bf16x8*>(&Ks[kkey[i] * LKS + kc8[i] * 8]) = kpre[i];
        #pragma unroll
        for (int i = 0; i < 4; ++i)
            *reinterpret_cast<bf16x8*>(&Vs[(vd + i * 32) * LVS + vc8 * 8]) = vpre[i];
        __syncthreads();

        // prefetch next tile into registers (overlaps with compute below)
        if (kt + 1 < ntmax) {
            const int k0n = (kt + 1) * 64;
            #pragma unroll
            for (int i = 0; i < 6; ++i) {
                const __bf16* src = (kc8[i] < 16)
                    ? kvb + ((size_t)(b * SEQ + k0n + kkey[i])) * (NH * 256) + h * 256 + kc8[i] * 8
                    : krope + ((size_t)(b * SEQ + k0n + kkey[i])) * QKR + (kc8[i] - 16) * 8;
                kpre[i] = *reinterpret_cast<const bf16x8*>(src);
            }
            #pragma unroll
            for (int i = 0; i < 4; ++i)
                vpre[i] = *reinterpret_cast<const bf16x8*>(Vg + (size_t)(vd + i * 32) * SEQ + k0n + vc8 * 8);
        }

        const int k0 = kt * 64;
        #pragma unroll
        for (int s = 0; s < 2; ++s) {
            if (kt > qs[s]) continue;      // strip 0 done after its diagonal

            // scores: S[16q x 64k], 4 key-subtiles x 6 d-chunks
            f32x4 sacc[4];
            #pragma unroll
            for (int t = 0; t < 4; ++t) {
                f32x4 a;
                #pragma unroll
                for (int r = 0; r < 4; ++r) a[r] = 0.f;
                #pragma unroll
                for (int c = 0; c < 6; ++c) {
                    bf16x8 kf = *reinterpret_cast<const bf16x8*>(&Ks[(t * 16 + n) * LKS + c * 32 + quad * 8]);
                    a = __builtin_amdgcn_mfma_f32_16x16x32_bf16(qfrag[s][c], kf, a, 0, 0, 0);
                }
                sacc[t] = a;
            }

            const int qg = qs[s] * 64 + wave * 16 + quad * 4;
            const bool diag = (kt == qs[s]);
            float mloc[4];
            #pragma unroll
            for (int r = 0; r < 4; ++r) mloc[r] = -1e30f;
            #pragma unroll
            for (int t = 0; t < 4; ++t) {
                int key = k0 + t * 16 + n;
                #pragma unroll
                for (int r = 0; r < 4; ++r) {
                    float sv = sacc[t][r] * scale;
                    if (diag) sv = (key <= qg + r) ? sv : -1e30f;
                    sacc[t][r] = sv;
                    mloc[r] = fmaxf(mloc[r], sv);
                }
            }
            #pragma unroll
            for (int off = 1; off < 16; off <<= 1)
                #pragma unroll
                for (int r = 0; r < 4; ++r)
                    mloc[r] = fmaxf(mloc[r], __shfl_xor(mloc[r], off, 64));
            float alpha[4], sum[4];
            #pragma unroll
            for (int r = 0; r < 4; ++r) {
                float mn = fmaxf(m_i[s][r], mloc[r]);
                alpha[r] = __expf(m_i[s][r] - mn);
                m_i[s][r] = mn;
                sum[r] = 0.f;
            }
            #pragma unroll
            for (int t = 0; t < 4; ++t)
                #pragma unroll
                for (int r = 0; r < 4; ++r) {
                    float p = __expf(sacc[t][r] - m_i[s][r]);
                    sum[r] += p;
                    Ps[s][wave * 16 * LPS + (quad * 4 + r) * LPS + t * 16 + n] = (__bf16)p;
                }
            #pragma unroll
            for (int off = 1; off < 16; off <<= 1)
                #pragma unroll
                for (int r = 0; r < 4; ++r)
                    sum[r] += __shfl_xor(sum[r], off, 64);
            #pragma unroll
            for (int r = 0; r < 4; ++r) l_i[s][r] = l_i[s][r] * alpha[r] + sum[r];
            #pragma unroll
            for (int i = 0; i < 8; ++i)
                #pragma unroll
                for (int r = 0; r < 4; ++r) Oa[s][i][r] *= alpha[r];

            // drain P writes (per-wave region; in-wave ordering only)
            __asm__ volatile("s_waitcnt lgkmcnt(0)" ::: "memory");

            // PV: O[16q x 128vd] += P[16x64] * V[64x128]
            #pragma unroll
            for (int kc = 0; kc < 2; ++kc) {
                bf16x8 pf = *reinterpret_cast<const bf16x8*>(&Ps[s][wave * 16 * LPS + n * LPS + kc * 32 + quad * 8]);
                #pragma unroll
                for (int vt = 0; vt < 8; ++vt) {
                    bf16x8 vf = *reinterpret_cast<const bf16x8*>(&Vs[(vt * 16 + n) * LVS + kc * 32 + quad * 8]);
                    Oa[s][vt] = __builtin_amdgcn_mfma_f32_16x16x32_bf16(pf, vf, Oa[s][vt], 0, 0, 0);
                }
            }
        }
    }

    // epilogue: both strips
    #pragma unroll
    for (int s = 0; s < 2; ++s)
        #pragma unroll
        for (int r = 0; r < 4; ++r) {
            float inv = 1.0f / l_i[s][r];
            int row = qs[s] * 64 + wave * 16 + quad * 4 + r;
            __bf16* op = ob + ((size_t)(b * SEQ + row)) * (NH * VD) + h * VD;
            #pragma unroll
            for (int vt = 0; vt < 8; ++vt)
                op[vt * 16 + n] = (__bf16)(Oa[s][vt][r] * inv);
        }
}

extern "C" void kernel_launch(void* const* d_in, const int* in_sizes, int n_in,
                              void* d_out, int out_size, void* d_ws, size_t ws_size,
                              hipStream_t stream)
{
    const float* x         = (const float*)d_in[0];
    const float* Wq        = (const float*)d_in[1];
    const float* Wkv_a     = (const float*)d_in[2];
    const float* kv_norm_w = (const float*)d_in[3];
    const float* Wkv_b     = (const float*)d_in[4];
    const float* Wo        = (const float*)d_in[5];
    float* out = (float*)d_out;

    // workspace layout (f32-unit offsets); aliasing noted
    float* ws = (float*)d_ws;
    __bf16* q_bf   = (__bf16*)ws;                              // 12,582,912 bf16
    float*  kv_a   = ws + 6291456;                             // 4096x640 f32
    __bf16* kv_b   = (__bf16*)(ws + 8912896);                  // 16,777,216 bf16
    float*  r3     = ws + 17301504;                            // xb then Vt (alias)
    __bf16* xb     = (__bf16*)r3;                              // 8,388,608 bf16
    __bf16* Vt     = (__bf16*)r3;                              // 8,388,608 bf16
    float*  r4     = ws + 21495808;                            // weights then attn_o (alias)
    __bf16* Wq_t   = (__bf16*)r4;                              // 6,291,456 bf16
    __bf16* Wkva_t = (__bf16*)(r4 + 3145728);                  // 1,310,720 bf16
    __bf16* Wkvb_t = (__bf16*)(r4 + 3801088);                  // 2,097,152 bf16
    __bf16* attn_o = (__bf16*)r4;                              // 8,388,608 bf16 (weights dead)
    __bf16* Wo_t   = (__bf16*)(ws + 27787264);                 // 4,194,304 bf16
    __bf16* c_kv_n = (__bf16*)(ws + 29884416);                 // 2,097,152 bf16
    __bf16* krope  = (__bf16*)(ws + 30932992);                 //   262,144 bf16
    // total ≈ 124.3 MB

    const int M = BATCH * SEQ;   // 4096
    dim3 blk(256);

    f32_to_bf16<<<(M * DM) / 1024, blk, 0, stream>>>(x, xb);
    transpose_w<<<dim3(3072 / 64, 2048 / 64), blk, 0, stream>>>(Wq, Wq_t, DM, NH * QKD);
    transpose_w<<<dim3(640 / 64, 2048 / 64), blk, 0, stream>>>(Wkv_a, Wkva_t, DM, KVL + QKR);
    transpose_w<<<dim3(4096 / 64, 512 / 64), blk, 0, stream>>>(Wkv_b, Wkvb_t, KVL, NH * 256);
    transpose_w<<<dim3(2048 / 64, 2048 / 64), blk, 0, stream>>>(Wo, Wo_t, NH * VD, DM);

    gemm_bf16<__bf16><<<dim3(3072 / 128, M / 128), blk, 0, stream>>>(xb, Wq_t, q_bf, DM, DM, DM, NH * QKD);
    gemm_bf16<float><<<dim3(640 / 128, M / 128), blk, 0, stream>>>(xb, Wkva_t, kv_a, DM, DM, DM, KVA_LD);

    rope_q_kernel<<<(BATCH * SEQ * NH * 32) / 256, blk, 0, stream>>>(q_bf);
    rope_k_kernel<<<(BATCH * SEQ * 32) / 256, blk, 0, stream>>>(kv_a, krope);
    rmsnorm_kernel<<<M, blk, 0, stream>>>(kv_a, kv_norm_w, c_kv_n);

    gemm_bf16<__bf16><<<dim3(4096 / 128, M / 128), blk, 0, stream>>>(c_kv_n, Wkvb_t, kv_b, KVL, KVL, KVL, NH * 256);

    build_vt<<<dim3(SEQ / 64, NH, BATCH), blk, 0, stream>>>(kv_b, Vt);

    attn_mfma<<<dim3(16, NH, BATCH), blk, 0, stream>>>(q_bf, kv_b, krope, Vt, attn_o);

    gemm_bf16<float><<<dim3(2048 / 128, M / 128), blk, 0, stream>>>(attn_o, Wo_t, out, NH * VD, NH * VD, NH * VD, DM);
}